// Round 2
// baseline (360.028 us; speedup 1.0000x reference)
//
#include <hip/hip_runtime.h>
#include <stdint.h>

// B=8, C=128, N=4096 (64x64), GROUPS=8 (16 ch/group)

typedef __attribute__((ext_vector_type(8))) short short8;
typedef __attribute__((ext_vector_type(4))) float f32x4;

#define MFMA_BF16(a, b, c) __builtin_amdgcn_mfma_f32_16x16x32_bf16((a), (b), (c), 0, 0, 0)

__device__ __forceinline__ unsigned short f2bf(float f) {
    unsigned int u = __builtin_bit_cast(unsigned int, f);
    u += 0x7FFFu + ((u >> 16) & 1u);   // RNE (finite values only)
    return (unsigned short)(u >> 16);
}

__device__ __forceinline__ short8 ldg8(const unsigned short* p) {
    return __builtin_bit_cast(short8, *(const uint4*)p);
}

// ---------------- Kernel 1: GroupNorm stats (mean, rstd) per (b,g) ----------------
__global__ __launch_bounds__(256) void k_stats(const float* __restrict__ x,
                                               float* __restrict__ stats) {
    int grp = blockIdx.x;                       // 0..63  (b*8+g); group slab is contiguous
    const float* p = x + (size_t)grp * 65536;
    float s = 0.f, sq = 0.f;
    for (int i = threadIdx.x * 4; i < 65536; i += 1024) {
        float4 v = *(const float4*)(p + i);
        s  += v.x + v.y + v.z + v.w;
        sq += v.x*v.x + v.y*v.y + v.z*v.z + v.w*v.w;
    }
#pragma unroll
    for (int m = 1; m < 64; m <<= 1) { s += __shfl_xor(s, m, 64); sq += __shfl_xor(sq, m, 64); }
    __shared__ float ss[4], ssq[4];
    int w = threadIdx.x >> 6;
    if ((threadIdx.x & 63) == 0) { ss[w] = s; ssq[w] = sq; }
    __syncthreads();
    if (threadIdx.x == 0) {
        float ts = ss[0] + ss[1] + ss[2] + ss[3];
        float tq = ssq[0] + ssq[1] + ssq[2] + ssq[3];
        float mean = ts * (1.f / 65536.f);
        float var  = tq * (1.f / 65536.f) - mean * mean;
        stats[grp * 2]     = mean;
        stats[grp * 2 + 1] = rsqrtf(var + 1e-5f);
    }
}

// ---------------- Kernel 2: fused GroupNorm-apply + QKV GEMM ----------------
// Writes Q,K as bf16 [b][n][c] (c contiguous), V as bf16 [b][c][n] (n contiguous).
__global__ __launch_bounds__(256) void k_qkv(const float* __restrict__ x,
                                             const float* __restrict__ stats,
                                             const float* __restrict__ gn_w,
                                             const float* __restrict__ gn_b,
                                             const float* __restrict__ qkv_w,
                                             const float* __restrict__ qkv_b,
                                             unsigned short* __restrict__ q_ws,
                                             unsigned short* __restrict__ k_ws,
                                             unsigned short* __restrict__ v_ws) {
    __shared__ unsigned short h_lds[64][136];   // [n][c], +8 pad
    const int tid  = threadIdx.x;
    const int b    = blockIdx.x >> 6;
    const int n0   = (blockIdx.x & 63) << 6;
    const int lane = tid & 63, wave = tid >> 6;
    const int l15  = lane & 15, q4 = lane >> 4;

    // normalize x tile -> bf16 -> h_lds[n][c]
    {
        int cb = tid >> 4;            // 0..15
        int nn = (tid & 15) << 2;     // 0..60
#pragma unroll
        for (int k = 0; k < 8; ++k) {
            int c = cb + (k << 4);
            float4 v = *(const float4*)(x + ((size_t)(b * 128 + c) << 12) + n0 + nn);
            int g = c >> 4;
            float mean = stats[(b * 8 + g) * 2];
            float rstd = stats[(b * 8 + g) * 2 + 1];
            float ga = gn_w[c] * rstd;
            float be = gn_b[c] - mean * ga;
            h_lds[nn + 0][c] = f2bf(v.x * ga + be);
            h_lds[nn + 1][c] = f2bf(v.y * ga + be);
            h_lds[nn + 2][c] = f2bf(v.z * ga + be);
            h_lds[nn + 3][c] = f2bf(v.w * ga + be);
        }
    }
    __syncthreads();

    short8 bfrag[4][4];               // [nt][ks]  B[k=c][n], n=l15
#pragma unroll
    for (int nt = 0; nt < 4; ++nt)
#pragma unroll
        for (int ks = 0; ks < 4; ++ks)
            bfrag[nt][ks] = *(const short8*)&h_lds[nt * 16 + l15][ks * 32 + q4 * 8];

#pragma unroll
    for (int ot = 0; ot < 6; ++ot) {
        int o0 = wave * 96 + ot * 16;                 // 16-row tile is purely Q, K, or V
        short8 af[4];                                 // A[m=o][k=c], m=l15
        const float* wp = qkv_w + (size_t)(o0 + l15) * 128 + q4 * 8;
#pragma unroll
        for (int ks = 0; ks < 4; ++ks) {
            float4 w0 = *(const float4*)(wp + ks * 32);
            float4 w1 = *(const float4*)(wp + ks * 32 + 4);
            short8 t;
            t[0] = (short)f2bf(w0.x); t[1] = (short)f2bf(w0.y);
            t[2] = (short)f2bf(w0.z); t[3] = (short)f2bf(w0.w);
            t[4] = (short)f2bf(w1.x); t[5] = (short)f2bf(w1.y);
            t[6] = (short)f2bf(w1.z); t[7] = (short)f2bf(w1.w);
            af[ks] = t;
        }
        float bias[4];
#pragma unroll
        for (int r = 0; r < 4; ++r) bias[r] = qkv_b[o0 + q4 * 4 + r];

#pragma unroll
        for (int nt = 0; nt < 4; ++nt) {
            f32x4 acc = {0.f, 0.f, 0.f, 0.f};
#pragma unroll
            for (int ks = 0; ks < 4; ++ks)
                acc = MFMA_BF16(af[ks], bfrag[nt][ks], acc);
            // D[row = o0+q4*4+r][col = n0+nt*16+l15]
            int n = n0 + nt * 16 + l15;
            if (o0 < 256) {           // Q or K: [n][c] layout, 4 consecutive c -> 8B store
                unsigned short* dst = (o0 < 128) ? q_ws : k_ws;
                int oo = (o0 < 128) ? o0 : (o0 - 128);
                unsigned int lo = (unsigned int)f2bf(acc[0] + bias[0]) |
                                  ((unsigned int)f2bf(acc[1] + bias[1]) << 16);
                unsigned int hi = (unsigned int)f2bf(acc[2] + bias[2]) |
                                  ((unsigned int)f2bf(acc[3] + bias[3]) << 16);
                uint2 pk; pk.x = lo; pk.y = hi;
                *(uint2*)&dst[((size_t)(b * 4096 + n) << 7) + oo + q4 * 4] = pk;
            } else {                  // V: [c][n] layout, scalar stores
#pragma unroll
                for (int r = 0; r < 4; ++r) {
                    int c = o0 - 256 + q4 * 4 + r;
                    v_ws[((size_t)(b * 128 + c) << 12) + n] = f2bf(acc[r] + bias[r]);
                }
            }
        }
    }
}

// ---------------- Kernel 3: flash attention + fused proj + residual ----------------
// block = (b, 64-row i-tile); wave w owns rows i0+16w..+15.
// O kept in D-layout O[i=q4*4+r][c]: softmax alpha & 1/l are pure per-register ops.
__global__ __launch_bounds__(256) void k_attn(const unsigned short* __restrict__ q_ws,
                                              const unsigned short* __restrict__ k_ws,
                                              const unsigned short* __restrict__ v_ws,
                                              const float* __restrict__ x,
                                              const float* __restrict__ proj_w,
                                              const float* __restrict__ proj_b,
                                              float* __restrict__ out) {
    __shared__ unsigned short K_lds[64][136];    // [j][c] during loop; [n][c] O-stage after
    __shared__ unsigned short V_lds[128][72];    // [c][j], +8 pad
    __shared__ unsigned short P_lds[4][16][72];  // per wave [i][j], +8 pad

    const int tid  = threadIdx.x;
    const int b    = blockIdx.x >> 6;
    const int i0   = (blockIdx.x & 63) << 6;
    const int lane = tid & 63, wave = tid >> 6;
    const int l15  = lane & 15, q4 = lane >> 4;
    const float scale = 0.08838834764831845f;    // 1/sqrt(128)

    short8 qf[4];                                // A[m=i][k=c], m=l15
    {
        const unsigned short* qp =
            q_ws + ((size_t)(b * 4096 + i0 + wave * 16 + l15) << 7) + q4 * 8;
#pragma unroll
        for (int ks = 0; ks < 4; ++ks) qf[ks] = ldg8(qp + ks * 32);
    }

    float mrow[4], lrow[4];
#pragma unroll
    for (int r = 0; r < 4; ++r) { mrow[r] = -1e30f; lrow[r] = 0.f; }
    f32x4 acc_o[8];                              // O[i=q4*4+r][c = ct*16 + l15]
#pragma unroll
    for (int ct = 0; ct < 8; ++ct) acc_o[ct] = (f32x4){0.f, 0.f, 0.f, 0.f};

    const unsigned short* kbase = k_ws + ((size_t)b << 19);
    const unsigned short* vbase = v_ws + ((size_t)b << 19);

    for (int it = 0; it < 64; ++it) {
        int j0 = it << 6;
        __syncthreads();                          // prior iter's LDS reads done
        {   // stage K tile [64 j][128 c]
            const uint4* src = (const uint4*)(kbase + ((size_t)(j0 + (tid >> 2)) << 7) + (tid & 3) * 32);
            uint4* dst = (uint4*)&K_lds[tid >> 2][(tid & 3) * 32];
            dst[0] = src[0]; dst[1] = src[1]; dst[2] = src[2]; dst[3] = src[3];
            // stage V tile [128 c][64 j]
            const uint4* vs = (const uint4*)(vbase + ((size_t)(tid >> 1) << 12) + j0 + (tid & 1) * 32);
            uint4* vd = (uint4*)&V_lds[tid >> 1][(tid & 1) * 32];
            vd[0] = vs[0]; vd[1] = vs[1]; vd[2] = vs[2]; vd[3] = vs[3];
        }
        __syncthreads();

        // S = scale * Q K^T : D row = i (q4*4+r), col = j (l15)
        f32x4 s[4];
#pragma unroll
        for (int jt = 0; jt < 4; ++jt) {
            f32x4 a = {0.f, 0.f, 0.f, 0.f};
#pragma unroll
            for (int ks = 0; ks < 4; ++ks) {
                short8 kf = *(const short8*)&K_lds[jt * 16 + l15][ks * 32 + q4 * 8];
                a = MFMA_BF16(qf[ks], kf, a);
            }
            s[jt] = a * scale;
        }

        // online softmax (row state lives in (quad, reg) space; reduce over l15 = j)
        float rm[4];
#pragma unroll
        for (int r = 0; r < 4; ++r)
            rm[r] = fmaxf(fmaxf(s[0][r], s[1][r]), fmaxf(s[2][r], s[3][r]));
#pragma unroll
        for (int msk = 1; msk < 16; msk <<= 1)
#pragma unroll
            for (int r = 0; r < 4; ++r)
                rm[r] = fmaxf(rm[r], __shfl_xor(rm[r], msk, 64));

        float al[4], rs[4];
#pragma unroll
        for (int r = 0; r < 4; ++r) {
            float mn = fmaxf(mrow[r], rm[r]);
            al[r] = __expf(mrow[r] - mn);
            mrow[r] = mn;
            rs[r] = 0.f;
        }
#pragma unroll
        for (int jt = 0; jt < 4; ++jt)
#pragma unroll
            for (int r = 0; r < 4; ++r) {
                float p = __expf(s[jt][r] - mrow[r]);
                rs[r] += p;
                P_lds[wave][q4 * 4 + r][jt * 16 + l15] = f2bf(p);
            }
#pragma unroll
        for (int msk = 1; msk < 16; msk <<= 1)
#pragma unroll
            for (int r = 0; r < 4; ++r)
                rs[r] += __shfl_xor(rs[r], msk, 64);
#pragma unroll
        for (int r = 0; r < 4; ++r) lrow[r] = lrow[r] * al[r] + rs[r];

        // rescale O rows by alpha — pure register op, row r lives in reg r
#pragma unroll
        for (int ct = 0; ct < 8; ++ct)
#pragma unroll
            for (int r = 0; r < 4; ++r) acc_o[ct][r] *= al[r];

        // O += P V^T : A = P[i][j] (m=l15), B = V^T[j][c] (n=l15) -> D[i][c]
#pragma unroll
        for (int ks = 0; ks < 2; ++ks) {
            short8 pf = *(const short8*)&P_lds[wave][l15][ks * 32 + q4 * 8];
#pragma unroll
            for (int ct = 0; ct < 8; ++ct) {
                short8 vf = *(const short8*)&V_lds[ct * 16 + l15][ks * 32 + q4 * 8];
                acc_o[ct] = MFMA_BF16(pf, vf, acc_o[ct]);
            }
        }
    }

    // normalize rows (register-local) and stage O into LDS as [n_local][c]
    __syncthreads();                              // done with K_lds as K
    {
        float rl[4];
#pragma unroll
        for (int r = 0; r < 4; ++r) rl[r] = 1.0f / lrow[r];
#pragma unroll
        for (int ct = 0; ct < 8; ++ct)
#pragma unroll
            for (int r = 0; r < 4; ++r)
                K_lds[wave * 16 + q4 * 4 + r][ct * 16 + l15] = f2bf(acc_o[ct][r] * rl[r]);
    }
    __syncthreads();

    // proj GEMM: out[o][n] = sum_c proj_w[o][c] * O[n][c]  + proj_b + x
    short8 bfrag[4][4];
#pragma unroll
    for (int nt = 0; nt < 4; ++nt)
#pragma unroll
        for (int ks = 0; ks < 4; ++ks)
            bfrag[nt][ks] = *(const short8*)&K_lds[nt * 16 + l15][ks * 32 + q4 * 8];

#pragma unroll
    for (int ot = 0; ot < 2; ++ot) {
        int o0 = wave * 32 + ot * 16;
        short8 af[4];
        const float* wp = proj_w + (size_t)(o0 + l15) * 128 + q4 * 8;
#pragma unroll
        for (int ks = 0; ks < 4; ++ks) {
            float4 w0 = *(const float4*)(wp + ks * 32);
            float4 w1 = *(const float4*)(wp + ks * 32 + 4);
            short8 t;
            t[0] = (short)f2bf(w0.x); t[1] = (short)f2bf(w0.y);
            t[2] = (short)f2bf(w0.z); t[3] = (short)f2bf(w0.w);
            t[4] = (short)f2bf(w1.x); t[5] = (short)f2bf(w1.y);
            t[6] = (short)f2bf(w1.z); t[7] = (short)f2bf(w1.w);
            af[ks] = t;
        }
        float pb[4];
#pragma unroll
        for (int r = 0; r < 4; ++r) pb[r] = proj_b[o0 + q4 * 4 + r];

#pragma unroll
        for (int nt = 0; nt < 4; ++nt) {
            f32x4 acc = {0.f, 0.f, 0.f, 0.f};
#pragma unroll
            for (int ks = 0; ks < 4; ++ks)
                acc = MFMA_BF16(af[ks], bfrag[nt][ks], acc);
#pragma unroll
            for (int r = 0; r < 4; ++r) {
                size_t idx = ((size_t)(b * 128 + o0 + q4 * 4 + r) << 12) + i0 + nt * 16 + l15;
                out[idx] = x[idx] + acc[r] + pb[r];
            }
        }
    }
}

// ---------------- launch ----------------
extern "C" void kernel_launch(void* const* d_in, const int* in_sizes, int n_in,
                              void* d_out, int out_size, void* d_ws, size_t ws_size,
                              hipStream_t stream) {
    const float* x      = (const float*)d_in[0];
    const float* gn_w   = (const float*)d_in[1];
    const float* gn_b   = (const float*)d_in[2];
    const float* qkv_w  = (const float*)d_in[3];
    const float* qkv_b  = (const float*)d_in[4];
    const float* proj_w = (const float*)d_in[5];
    const float* proj_b = (const float*)d_in[6];
    float* out = (float*)d_out;

    char* ws = (char*)d_ws;
    float* stats = (float*)ws;                                   // 64*2 floats
    unsigned short* q_ws = (unsigned short*)(ws + 1024);         // 8 MB each
    unsigned short* k_ws = q_ws + (size_t)8 * 4096 * 128;
    unsigned short* v_ws = k_ws + (size_t)8 * 4096 * 128;

    k_stats<<<64, 256, 0, stream>>>(x, stats);
    k_qkv<<<512, 256, 0, stream>>>(x, stats, gn_w, gn_b, qkv_w, qkv_b, q_ws, k_ws, v_ws);
    k_attn<<<512, 256, 0, stream>>>(q_ws, k_ws, v_ws, x, proj_w, proj_b, out);
}